// Round 4
// baseline (187.696 us; speedup 1.0000x reference)
//
#include <hip/hip_runtime.h>
#include <math.h>

#define NUM_CLASSES 1000
#define NV4 250            // float4 chunks per row (1000 floats)
#define BATCH 16384
#define NBLOCKS (BATCH / 4)
#define NSLOTS 64
#define SLOT_STRIDE 16     // floats -> 64 B apart, one cacheline per slot

// One wave (64 lanes) per row, 4 rows per 256-thread block. Online-softmax
// per-lane stats + one 6-step butterfly. Block partial -> atomicAdd into one
// of 64 contention-spread slots (64-long chains @ ~13 ns/atomic, overlapped
// with block retirement — R3 showed ONE shared address costs 4096*13ns=52us).
// Last block (ticket counter) sums the slots and writes the mean.
__global__ __launch_bounds__(256) void row_loss_kernel(
    const float* __restrict__ logits,
    const int* __restrict__ targets,
    float* __restrict__ slots,        // [NSLOTS * SLOT_STRIDE], zeroed
    unsigned* __restrict__ ticket,    // zeroed
    float* __restrict__ out) {
  const int wave = threadIdx.x >> 6;   // 0..3
  const int lane = threadIdx.x & 63;
  const int b = blockIdx.x * 4 + wave;

  const float4* row = (const float4*)(logits + (size_t)b * NUM_CLASSES);
  const int c = __builtin_amdgcn_readfirstlane(targets[b]);  // wave-uniform

  float4 v[4];
#pragma unroll
  for (int i = 0; i < 4; ++i) {
    const int j = lane + 64 * i;
    if (j < NV4) v[i] = row[j];
    else v[i] = make_float4(-INFINITY, -INFINITY, -INFINITY, -INFINITY);
  }

  float m = -INFINITY;
#pragma unroll
  for (int i = 0; i < 4; ++i)
    m = fmaxf(m, fmaxf(fmaxf(v[i].x, v[i].y), fmaxf(v[i].z, v[i].w)));

  float se = 0.f;   // sum exp(x - m)   (per-lane m for now)
  float ws = 0.f;   // sum_{k != c} x_k / (|k-c|+1)
  float tw = 0.f;   // sum_{k != c} 1 / (|k-c|+1)
  float lc = 0.f;   // x_c
#pragma unroll
  for (int i = 0; i < 4; ++i) {
    const float xs[4] = {v[i].x, v[i].y, v[i].z, v[i].w};
    const int k0 = (lane + 64 * i) * 4;
#pragma unroll
    for (int e = 0; e < 4; ++e) {
      const int k = k0 + e;
      const float x = xs[e];
      se += __expf(x - m);                 // pad: exp(-inf) = 0
      if (k < NUM_CLASSES) {
        if (k == c) {
          lc = x;
        } else {
          const float w = __builtin_amdgcn_rcpf((float)(abs(k - c) + 1));
          ws = fmaf(w, x, ws);
          tw += w;
        }
      }
    }
  }

  // single butterfly merging (m, se) online-softmax style + 3 plain sums
#pragma unroll
  for (int o = 32; o > 0; o >>= 1) {
    const float mo  = __shfl_xor(m, o);
    const float seo = __shfl_xor(se, o);
    const float wso = __shfl_xor(ws, o);
    const float two = __shfl_xor(tw, o);
    const float lco = __shfl_xor(lc, o);
    const float nm = fmaxf(m, mo);
    se = se * __expf(m - nm) + seo * __expf(mo - nm);
    m = nm;
    ws += wso;
    tw += two;
    lc += lco;
  }

  __shared__ float sw[4];
  __shared__ int isLast;
  if (lane == 0) {
    // smoothing row of M sums to exactly 1.0 -> loss = lse - dot(M_row, x)
    sw[wave] = m + __logf(se) - (0.9f * lc + 0.1f * (ws / tw));
  }
  __syncthreads();
  if (threadIdx.x == 0) {
    const float bp = (sw[0] + sw[1] + sw[2] + sw[3]) * (1.0f / (float)BATCH);
    atomicAdd(&slots[(blockIdx.x & (NSLOTS - 1)) * SLOT_STRIDE], bp);
    __threadfence();  // slot add visible before ticket increment
    const unsigned t = atomicAdd(ticket, 1u);
    isLast = (t == (unsigned)(NBLOCKS - 1)) ? 1 : 0;
  }
  __syncthreads();
  if (isLast && threadIdx.x < NSLOTS) {
    // agent-scope acquire loads: safe vs non-coherent per-XCD L2s
    float s = __hip_atomic_load(&slots[threadIdx.x * SLOT_STRIDE],
                                __ATOMIC_ACQUIRE, __HIP_MEMORY_SCOPE_AGENT);
#pragma unroll
    for (int o = 32; o > 0; o >>= 1) s += __shfl_xor(s, o);
    if (threadIdx.x == 0) out[0] = s;
  }
}

extern "C" void kernel_launch(void* const* d_in, const int* in_sizes, int n_in,
                              void* d_out, int out_size, void* d_ws, size_t ws_size,
                              hipStream_t stream) {
  const float* logits = (const float*)d_in[0];
  const int* targets = (const int*)d_in[1];
  float* out = (float*)d_out;
  float* slots = (float*)d_ws;                                // 4 KB
  unsigned* ticket = (unsigned*)((char*)d_ws + NSLOTS * SLOT_STRIDE * 4);

  // zero slots + ticket (d_ws is poisoned 0xAA before every call)
  hipMemsetAsync(d_ws, 0, NSLOTS * SLOT_STRIDE * 4 + 64, stream);
  row_loss_kernel<<<NBLOCKS, 256, 0, stream>>>(logits, targets, slots, ticket, out);
}

// Round 5
// 92.683 us; speedup vs baseline: 2.0251x; 2.0251x over previous
//
#include <hip/hip_runtime.h>
#include <math.h>

#define NUM_CLASSES 1000
#define NV4 250            // float4 chunks per row (1000 floats)
#define BATCH 16384
#define NBLOCKS (BATCH / 4)

// One wave (64 lanes) per row, 4 rows per 256-thread block. Online-softmax:
// per-lane (max, sum-exp) built during the load pass, then ONE 6-step
// butterfly merges all five row statistics. Each block writes a single
// non-atomic partial (sum of its 4 row losses) — no atomics, no fences
// (R3/R4 measured: same-address device atomics ~13 ns each serialized;
// per-block __threadfence is worse). A tiny second kernel reduces 4096
// partials.
__global__ __launch_bounds__(256) void row_loss_kernel(
    const float* __restrict__ logits,
    const int* __restrict__ targets,
    float* __restrict__ partials) {
  const int wave = threadIdx.x >> 6;   // 0..3
  const int lane = threadIdx.x & 63;
  const int b = blockIdx.x * 4 + wave;

  const float4* row = (const float4*)(logits + (size_t)b * NUM_CLASSES);
  const int c = __builtin_amdgcn_readfirstlane(targets[b]);  // wave-uniform

  float4 v[4];
#pragma unroll
  for (int i = 0; i < 4; ++i) {
    const int j = lane + 64 * i;
    if (j < NV4) v[i] = row[j];
    else v[i] = make_float4(-INFINITY, -INFINITY, -INFINITY, -INFINITY);
  }

  float m = -INFINITY;
#pragma unroll
  for (int i = 0; i < 4; ++i)
    m = fmaxf(m, fmaxf(fmaxf(v[i].x, v[i].y), fmaxf(v[i].z, v[i].w)));

  float se = 0.f;   // sum exp(x - m)   (per-lane m for now)
  float ws = 0.f;   // sum_{k != c} x_k / (|k-c|+1)
  float tw = 0.f;   // sum_{k != c} 1 / (|k-c|+1)
  float lc = 0.f;   // x_c
#pragma unroll
  for (int i = 0; i < 4; ++i) {
    const float xs[4] = {v[i].x, v[i].y, v[i].z, v[i].w};
    const int k0 = (lane + 64 * i) * 4;
#pragma unroll
    for (int e = 0; e < 4; ++e) {
      const int k = k0 + e;
      const float x = xs[e];
      se += __expf(x - m);                 // pad: exp(-inf) = 0
      if (k < NUM_CLASSES) {
        if (k == c) {
          lc = x;
        } else {
          const float w = __builtin_amdgcn_rcpf((float)(abs(k - c) + 1));
          ws = fmaf(w, x, ws);
          tw += w;
        }
      }
    }
  }

  // single butterfly merging (m, se) online-softmax style + 3 plain sums
#pragma unroll
  for (int o = 32; o > 0; o >>= 1) {
    const float mo  = __shfl_xor(m, o);
    const float seo = __shfl_xor(se, o);
    const float wso = __shfl_xor(ws, o);
    const float two = __shfl_xor(tw, o);
    const float lco = __shfl_xor(lc, o);
    const float nm = fmaxf(m, mo);
    se = se * __expf(m - nm) + seo * __expf(mo - nm);
    m = nm;
    ws += wso;
    tw += two;
    lc += lco;
  }

  __shared__ float sw[4];
  if (lane == 0) {
    // smoothing row of M sums to exactly 1.0 -> loss = lse - dot(M_row, x)
    sw[wave] = m + __logf(se) - (0.9f * lc + 0.1f * (ws / tw));
  }
  __syncthreads();
  if (threadIdx.x == 0) {
    partials[blockIdx.x] = (sw[0] + sw[1]) + (sw[2] + sw[3]);
  }
}

// Reduce 4096 block-partials -> mean. 256 threads, 1024 float4 loads.
__global__ __launch_bounds__(256) void final_reduce_kernel(
    const float4* __restrict__ partials, float* __restrict__ out) {
  float s = 0.f;
#pragma unroll
  for (int i = 0; i < NBLOCKS / 4 / 256; ++i) {
    const float4 t = partials[threadIdx.x + 256 * i];
    s += (t.x + t.y) + (t.z + t.w);
  }
#pragma unroll
  for (int o = 32; o > 0; o >>= 1) s += __shfl_xor(s, o);
  __shared__ float sw[4];
  if ((threadIdx.x & 63) == 0) sw[threadIdx.x >> 6] = s;
  __syncthreads();
  if (threadIdx.x == 0) {
    out[0] = ((sw[0] + sw[1]) + (sw[2] + sw[3])) * (1.0f / (float)BATCH);
  }
}

extern "C" void kernel_launch(void* const* d_in, const int* in_sizes, int n_in,
                              void* d_out, int out_size, void* d_ws, size_t ws_size,
                              hipStream_t stream) {
  const float* logits = (const float*)d_in[0];
  const int* targets = (const int*)d_in[1];
  float* out = (float*)d_out;
  float* partials = (float*)d_ws;   // NBLOCKS floats = 16 KB scratch

  row_loss_kernel<<<NBLOCKS, 256, 0, stream>>>(logits, targets, partials);
  final_reduce_kernel<<<1, 256, 0, stream>>>((const float4*)partials, out);
}